// Round 9
// baseline (348.670 us; speedup 1.0000x reference)
//
#include <hip/hip_runtime.h>
#include <stdint.h>

#define BATCH 16
#define NBOX  32768
#define PRE   4096
#define POST  512
#define GRIDW 13
#define NCELL (GRIDW * GRIDW)     // 169 cells of 5.5 units
#define CELLCAP 128

// LDS pad for u64 bitonic arrays: slot(i) = i + (i>>4).
#define PADIDX(i) ((i) + ((i) >> 4))

typedef unsigned long long u64;
typedef unsigned int u32;
typedef unsigned short u16;

__device__ inline u64 shfl64(u64 v, int src) {
    int lo = __shfl((int)(v & 0xffffffffULL), src);
    int hi = __shfl((int)(v >> 32), src);
    return ((u64)(u32)hi << 32) | (u32)lo;
}

// ---------------------------------------------------------------------------
// K1: fused keygen + LDS bitonic sort of a 4096-key chunk (ascending).
// key = (~score_bits)<<32 | box_index  -> ascending == lax.top_k order.
// ---------------------------------------------------------------------------
__global__ __launch_bounds__(1024) void k_sortkeys4096(const float* __restrict__ cls,
                                                       u64* __restrict__ out) {
    __shared__ u64 s[PRE + (PRE >> 4)];
    int g = blockIdx.x;                   // global chunk: g = b*8 + c
    u64* dst = out + (size_t)g * PRE;
    int tid = threadIdx.x;
    for (int i = tid; i < PRE; i += 1024) {
        int idx = g * PRE + i;            // global box index (b*NBOX + n)
        const float* c = cls + (size_t)idx * 3;
        float sc = fmaxf(fmaxf(c[0], c[1]), c[2]);
        u32 sb = __float_as_uint(sc);     // scores >= 0 -> monotonic bits
        s[PADIDX(i)] = ((u64)(~sb) << 32) | (u32)(idx & (NBOX - 1));
    }
    for (int k = 2; k <= PRE; k <<= 1) {
        for (int jj = k >> 1; jj > 0; jj >>= 1) {
            __syncthreads();
            for (int p = tid; p < PRE / 2; p += 1024) {
                int i = 2 * p - (p & (jj - 1));
                int l = i + jj;
                bool asc = ((i & k) == 0);
                u64 a = s[PADIDX(i)], b = s[PADIDX(l)];
                if ((a > b) == asc) { s[PADIDX(i)] = b; s[PADIDX(l)] = a; }
            }
        }
    }
    __syncthreads();
    for (int i = tid; i < PRE; i += 1024) dst[i] = s[PADIDX(i)];
}

// ---------------------------------------------------------------------------
// K2: merge-path merge of two ascending 4096-lists, keep smallest 4096.
// ---------------------------------------------------------------------------
__global__ __launch_bounds__(256) void k_mergepath(const u64* __restrict__ in,
                                                   u64* __restrict__ out, int npairs) {
    __shared__ u64 sA[PRE], sB[PRE];
    int b = blockIdx.x / npairs, p = blockIdx.x % npairs;
    const u64* A  = in + ((size_t)b * npairs * 2 + (size_t)p * 2) * PRE;
    const u64* Bp = A + PRE;
    u64* dst = out + ((size_t)b * npairs + p) * PRE;
    int tid = threadIdx.x;
    for (int i = tid; i < PRE; i += 256) { sA[i] = A[i]; sB[i] = Bp[i]; }
    __syncthreads();
    int d = tid * 16;
    int lo = d > PRE ? d - PRE : 0;
    int hi = d < PRE ? d : PRE;
    while (lo < hi) {
        int mid = (lo + hi) >> 1;
        if (sA[mid] < sB[d - 1 - mid]) lo = mid + 1; else hi = mid;
    }
    int a = lo, bi = d - lo;
    u64 av = a  < PRE ? sA[a]  : ~0ULL;
    u64 bv = bi < PRE ? sB[bi] : ~0ULL;
    u64 res[16];
    #pragma unroll
    for (int q = 0; q < 16; ++q) {
        bool ta = av < bv;
        res[q] = ta ? av : bv;
        if (ta) { ++a;  av = a  < PRE ? sA[a]  : ~0ULL; }
        else    { ++bi; bv = bi < PRE ? sB[bi] : ~0ULL; }
    }
    #pragma unroll
    for (int q = 0; q < 16; ++q) dst[d + q] = res[q];
}

// ---------------------------------------------------------------------------
// K3: coord extraction + spatial binning (1 thread = 1 candidate).
// cbox = {x1,y1,x2,y2} (exact rn ops), car = area. Bin by RAW center
// (bp[0],bp[1]) into 13x13 cells of 5.5 units: any overlapping pair has
// |dcenter| < 5 < 5.5 per axis => cell diff <= 1 (floor monotone + margin).
// ---------------------------------------------------------------------------
__global__ __launch_bounds__(256) void k_coords(const u64* __restrict__ topkeys,
                                                const float* __restrict__ boxes,
                                                float4* __restrict__ cbox,
                                                float* __restrict__ car,
                                                u16* __restrict__ cellof,
                                                u16* __restrict__ cells,
                                                u32* __restrict__ cellcnt) {
    int g = blockIdx.x * 256 + threadIdx.x;   // 0 .. B*PRE-1
    int b = g >> 12;                          // PRE = 4096
    u64 key = topkeys[g];
    int n = (int)(key & 0xffffffffULL);
    const float* bp = boxes + ((size_t)b * NBOX + n) * 7;
    float cx = bp[0], cy = bp[1], dx = bp[3], dy = bp[4];
    float hx = __fmul_rn(dx, 0.5f), hy = __fmul_rn(dy, 0.5f);
    float x1 = __fsub_rn(cx, hx), x2 = __fadd_rn(cx, hx);
    float y1 = __fsub_rn(cy, hy), y2 = __fadd_rn(cy, hy);
    cbox[g] = make_float4(x1, y1, x2, y2);
    car[g] = __fmul_rn(__fsub_rn(x2, x1), __fsub_rn(y2, y1));
    int cix = (int)(cx * (1.0f / 5.5f)); cix = cix < 0 ? 0 : (cix > GRIDW - 1 ? GRIDW - 1 : cix);
    int ciy = (int)(cy * (1.0f / 5.5f)); ciy = ciy < 0 ? 0 : (ciy > GRIDW - 1 ? GRIDW - 1 : ciy);
    int cl = ciy * GRIDW + cix;
    cellof[g] = (u16)cl;
    int cell = b * NCELL + cl;
    u32 slot = atomicAdd(&cellcnt[cell], 1u);
    if (slot < CELLCAP) cells[((size_t)cell << 7) + slot] = (u16)(g & (PRE - 1));
}

// ---------------------------------------------------------------------------
// K4: spatially-pruned suppression lists. 1 thread = row i (single writer).
// Scans 3x3 neighbor cells; exact predicate: j>i, inter>0, and the
// division-free threshold RN32(p/q) >= 0.7f <=> p > (0.7f-2^-25)*q in f64.
// Row = 8 u16: [count, up to 7 entries]; overflow -> per-batch spill.
// ---------------------------------------------------------------------------
__global__ __launch_bounds__(256) void k_iou(const float4* __restrict__ cbox,
                                             const float* __restrict__ car,
                                             const u16* __restrict__ cellof,
                                             const u16* __restrict__ cells,
                                             const u32* __restrict__ cellcnt,
                                             u16* __restrict__ lists,
                                             u32* __restrict__ spcnt,
                                             u32* __restrict__ spill) {
    int g = blockIdx.x * 256 + threadIdx.x;   // 0 .. B*PRE-1
    int b = g >> 12;
    int i = g & (PRE - 1);
    size_t base = (size_t)b * PRE;
    float4 bi = cbox[base + i];
    float ai = car[base + i];
    const double M = (double)0.7f - 0x1p-25;   // exact rounding boundary
    int c0 = cellof[g];
    int cxi = c0 % GRIDW, cyi = c0 / GRIDW;
    int y0 = cyi > 0 ? cyi - 1 : 0, y1 = cyi < GRIDW - 1 ? cyi + 1 : GRIDW - 1;
    int x0 = cxi > 0 ? cxi - 1 : 0, x1 = cxi < GRIDW - 1 ? cxi + 1 : GRIDW - 1;
    int cnt = 0;
    u16 own[7] = {0, 0, 0, 0, 0, 0, 0};
    for (int ny = y0; ny <= y1; ++ny)
    for (int nx = x0; nx <= x1; ++nx) {
        int cell = b * NCELL + ny * GRIDW + nx;
        int m = (int)cellcnt[cell]; if (m > CELLCAP) m = CELLCAP;
        const u16* cl = cells + ((size_t)cell << 7);
        for (int s = 0; s < m; ++s) {
            int j = cl[s];
            if (j <= i) continue;
            float4 bj = cbox[base + j];
            float ix = fmaxf(__fsub_rn(fminf(bi.z, bj.z), fmaxf(bi.x, bj.x)), 0.0f);
            float iy = fmaxf(__fsub_rn(fminf(bi.w, bj.w), fmaxf(bi.y, bj.y)), 0.0f);
            float inter = __fmul_rn(ix, iy);
            if (inter > 0.0f) {
                float aj = car[base + j];
                float q = __fadd_rn(__fsub_rn(__fadd_rn(aj, ai), inter), 1e-8f);
                if ((double)inter > M * (double)q) {
                    if (cnt < 7) own[cnt] = (u16)j;
                    else {
                        u32 sp = atomicAdd(&spcnt[b], 1u);
                        if (sp < 4096) spill[(b << 12) + sp] = ((u32)i << 16) | (u32)j;
                    }
                    ++cnt;
                }
            }
        }
    }
    uint4 row;
    row.x = (u32)(cnt > 65535 ? 65535 : cnt) | ((u32)own[0] << 16);
    row.y = (u32)own[1] | ((u32)own[2] << 16);
    row.z = (u32)own[3] | ((u32)own[4] << 16);
    row.w = (u32)own[5] | ((u32)own[6] << 16);
    ((uint4*)lists)[g] = row;
}

// ---------------------------------------------------------------------------
// K5: single-thread word-sequential greedy walk (proven round 8).
// ---------------------------------------------------------------------------
__global__ __launch_bounds__(256) void k_walk(const u16* __restrict__ lists,
                                              const u32* __restrict__ spcnt,
                                              const u32* __restrict__ spill,
                                              const u64* __restrict__ topkeys,
                                              const float* __restrict__ boxes,
                                              const float* __restrict__ cls,
                                              float* __restrict__ out) {
    __shared__ uint4 lrow[PRE];        // 64 KB: (count,7 entries) per row
    __shared__ u64   smask[64];        // active mask
    __shared__ u64   haslw[64];        // has-suppression-list bit per row
    __shared__ u32   lspill[4096];     // 16 KB spill mirror
    __shared__ int   ssel[POST];
    __shared__ int   scnt, ssp;
    int b = blockIdx.x;
    int tid = threadIdx.x;
    const u64* keys = topkeys + (size_t)b * PRE;
    const uint4* listv = (const uint4*)(lists + ((size_t)b * PRE) * 8);

    if (tid < 64) { smask[tid] = ~0ULL; haslw[tid] = 0ULL; }
    if (tid == 0) { u32 s = spcnt[b]; ssp = s > 4096u ? 4096 : (int)s; }
    __syncthreads();
    for (int i = tid; i < PRE; i += 256) {
        uint4 row = listv[i];
        lrow[i] = row;
        if (row.x & 0xFFFFu) atomicOr(&haslw[i >> 6], 1ULL << (i & 63));
    }
    __syncthreads();
    int spn = ssp;
    for (int q = tid; q < spn; q += 256) lspill[q] = spill[(b << 12) + q];
    __syncthreads();

    if (tid == 0) {
        int cnt = 0;
        for (int wd = 0; wd < 64 && cnt < POST; ++wd) {
            asm volatile("s_waitcnt lgkmcnt(0)" ::: "memory");
            u64 w  = smask[wd];
            u64 hl = haslw[wd];
            while (w) {
                int t = __ffsll(w) - 1;
                w &= w - 1;
                int i = (wd << 6) + t;
                ssel[cnt++] = i;
                if (cnt == POST) break;
                if ((hl >> t) & 1ULL) {
                    uint4 row = lrow[i];           // one ds_read_b128
                    int c = (int)(row.x & 0xFFFFu);
                    int e;
                    #define APPLY(e) do { \
                        if ((e >> 6) == wd) w &= ~(1ULL << (e & 63)); \
                        else atomicAnd(&smask[e >> 6], ~(1ULL << (e & 63))); \
                    } while (0)
                    e = (int)(row.x >> 16);     if (c > 0) APPLY(e);
                    e = (int)(row.y & 0xFFFFu); if (c > 1) APPLY(e);
                    e = (int)(row.y >> 16);     if (c > 2) APPLY(e);
                    e = (int)(row.z & 0xFFFFu); if (c > 3) APPLY(e);
                    e = (int)(row.z >> 16);     if (c > 4) APPLY(e);
                    e = (int)(row.w & 0xFFFFu); if (c > 5) APPLY(e);
                    e = (int)(row.w >> 16);     if (c > 6) APPLY(e);
                    if (c > 7) {                   // rare overflow: scan spill
                        for (int q = 0; q < spn; ++q) {
                            u32 en = lspill[q];
                            if ((int)(en >> 16) == i) {
                                int e2 = (int)(en & 0xFFFFu);
                                APPLY(e2);
                            }
                        }
                    }
                    #undef APPLY
                }
            }
        }
        scnt = cnt;
    }
    __syncthreads();
    int cnt = scnt;
    for (int k = tid; k < POST; k += 256) if (k >= cnt) ssel[k] = -1;
    __syncthreads();

    const int R1 = BATCH * POST * 7;
    const int R2 = R1 + BATCH * POST;
    for (int k = tid; k < POST; k += 256) {
        int j = ssel[k];
        float* ro = out + ((size_t)b * POST + k) * 7;
        float score = 0.0f, labelf = 1.0f;
        if (j >= 0) {
            u64 key = keys[j];
            int n = (int)(key & 0xffffffffULL);
            const float* bp = boxes + ((size_t)b * NBOX + n) * 7;
            #pragma unroll
            for (int c = 0; c < 7; ++c) ro[c] = bp[c];
            score = __uint_as_float(~(u32)(key >> 32));
            const float* cp = cls + ((size_t)b * NBOX + n) * 3;
            float c0 = cp[0], c1 = cp[1], c2 = cp[2];
            int lab = 0; float best = c0;
            if (c1 > best) { best = c1; lab = 1; }
            if (c2 > best) { lab = 2; }
            labelf = (float)(lab + 1);
        } else {
            #pragma unroll
            for (int c = 0; c < 7; ++c) ro[c] = 0.0f;
        }
        out[R1 + b * POST + k] = score;
        out[R2 + b * POST + k] = labelf;
    }
}

// ---------------------------------------------------------------------------
// Fallback NMS (round-0, proven), used only if ws is too small.
// ---------------------------------------------------------------------------
__global__ __launch_bounds__(1024) void k_nms(const u64* __restrict__ topkeys,
                                              const float* __restrict__ boxes,
                                              const float* __restrict__ cls,
                                              float* __restrict__ out) {
    __shared__ float sx1[PRE], sy1[PRE], sx2[PRE], sy2[PRE], sarea[PRE];
    __shared__ int   sorig[PRE];
    __shared__ u64   smask[PRE / 64];
    __shared__ int   ssel[POST];
    __shared__ int   scur;
    int b = blockIdx.x;
    int tid = threadIdx.x;
    const u64* keys = topkeys + (size_t)b * PRE;

    for (int i = tid; i < PRE; i += 1024) {
        u64 key = keys[i];
        int n = (int)(key & 0xffffffffULL);
        sorig[i] = n;
        const float* bp = boxes + ((size_t)b * NBOX + n) * 7;
        float cx = bp[0], cy = bp[1], dx = bp[3], dy = bp[4];
        float hx = __fmul_rn(dx, 0.5f), hy = __fmul_rn(dy, 0.5f);
        float x1 = __fsub_rn(cx, hx), x2 = __fadd_rn(cx, hx);
        float y1 = __fsub_rn(cy, hy), y2 = __fadd_rn(cy, hy);
        sx1[i] = x1; sx2[i] = x2; sy1[i] = y1; sy2[i] = y2;
        sarea[i] = __fmul_rn(__fsub_rn(x2, x1), __fsub_rn(y2, y1));
    }
    if (tid < PRE / 64) smask[tid] = ~0ULL;
    __syncthreads();

    int lane = tid & 63;
    int wv   = tid >> 6;
    for (int r = 0; r < POST; ++r) {
        if (tid < 64) {
            u64 w = smask[lane];
            u64 nz = __ballot(w != 0ULL);
            int j = -1;
            if (nz) {
                int fw = __ffsll(nz) - 1;
                u64 wf = shfl64(w, fw);
                j = (fw << 6) + __ffsll(wf) - 1;
            }
            if (lane == 0) { scur = j; ssel[r] = j; }
        }
        __syncthreads();
        int j = scur;
        if (j < 0) {
            for (int k = r + tid; k < POST; k += 1024) ssel[k] = -1;
            __syncthreads();
            break;
        }
        float x1j = sx1[j], x2j = sx2[j], y1j = sy1[j], y2j = sy2[j], aj = sarea[j];
        for (int wd = wv * 4; wd < wv * 4 + 4; ++wd) {
            u64 m = smask[wd];
            if (m == 0ULL) continue;
            int i = (wd << 6) + lane;
            float ix = fmaxf(__fsub_rn(fminf(sx2[i], x2j), fmaxf(sx1[i], x1j)), 0.0f);
            float iy = fmaxf(__fsub_rn(fminf(sy2[i], y2j), fmaxf(sy1[i], y1j)), 0.0f);
            float inter = __fmul_rn(ix, iy);
            float denom = __fadd_rn(__fsub_rn(__fadd_rn(sarea[i], aj), inter), 1e-8f);
            float iou = __fdiv_rn(inter, denom);
            u64 clr = __ballot(!(iou < 0.7f));
            if (lane == 0) smask[wd] = m & ~clr;
        }
        __syncthreads();
    }

    const int R1 = BATCH * POST * 7;
    const int R2 = R1 + BATCH * POST;
    for (int k = tid; k < POST; k += 1024) {
        int j = ssel[k];
        float* ro = out + ((size_t)b * POST + k) * 7;
        float score = 0.0f, labelf = 1.0f;
        if (j >= 0) {
            int n = sorig[j];
            const float* bp = boxes + ((size_t)b * NBOX + n) * 7;
            #pragma unroll
            for (int c = 0; c < 7; ++c) ro[c] = bp[c];
            u64 key = keys[j];
            score = __uint_as_float(~(u32)(key >> 32));
            const float* cp = cls + ((size_t)b * NBOX + n) * 3;
            float c0 = cp[0], c1 = cp[1], c2 = cp[2];
            int lab = 0; float best = c0;
            if (c1 > best) { best = c1; lab = 1; }
            if (c2 > best) { lab = 2; }
            labelf = (float)(lab + 1);
        } else {
            #pragma unroll
            for (int c = 0; c < 7; ++c) ro[c] = 0.0f;
        }
        out[R1 + b * POST + k] = score;
        out[R2 + b * POST + k] = labelf;
    }
}

extern "C" void kernel_launch(void* const* d_in, const int* in_sizes, int n_in,
                              void* d_out, int out_size, void* d_ws, size_t ws_size,
                              hipStream_t stream) {
    const float* boxes = (const float*)d_in[0]; // (B,N,7)
    const float* cls   = (const float*)d_in[1]; // (B,N,3)
    float* out = (float*)d_out;

    char* ws = (char*)d_ws;
    u64*    keysA   = (u64*)(ws + 0);                 // 4 MB
    u64*    keysB   = (u64*)(ws + 4194304);           // 4 MB
    float4* cbox    = (float4*)(ws + 8388608);        // 1 MB {x1,y1,x2,y2}
    float*  car     = (float*)(ws + 9437184);         // 256 KB areas
    u16*    cellof  = (u16*)(ws + 9699328);           // 128 KB cell of candidate
    u32*    spcnt   = (u32*)(ws + 9830400);           // 64 B   (zeroed)
    u32*    cellcnt = (u32*)(ws + 9830464);           // 10816 B (zeroed)
    u32*    spill   = (u32*)(ws + 9841280);           // 256 KB
    u16*    cells   = (u16*)(ws + 10103424);          // 676 KB cell lists
    u16*    lists   = (u16*)(ws + 10795648);          // 1 MB row lists
    const size_t NEED = 10795648 + (size_t)BATCH * PRE * 8 * sizeof(u16); // 11,844,224

    k_sortkeys4096<<<BATCH * 8, 1024, 0, stream>>>(cls, keysB);
    k_mergepath<<<BATCH * 4, 256, 0, stream>>>(keysB, keysA, 4);   // 8 -> 4
    k_mergepath<<<BATCH * 2, 256, 0, stream>>>(keysA, keysB, 2);   // 4 -> 2
    k_mergepath<<<BATCH, 256, 0, stream>>>(keysB, keysA, 1);       // 2 -> 1: topkeys

    if (ws_size >= NEED) {
        hipMemsetAsync(ws + 9830400, 0, 64 + 10816, stream);   // spcnt + cellcnt
        k_coords<<<(BATCH * PRE) / 256, 256, 0, stream>>>(keysA, boxes, cbox, car,
                                                          cellof, cells, cellcnt);
        k_iou<<<(BATCH * PRE) / 256, 256, 0, stream>>>(cbox, car, cellof, cells,
                                                       cellcnt, lists, spcnt, spill);
        k_walk<<<BATCH, 256, 0, stream>>>(lists, spcnt, spill,
                                          keysA, boxes, cls, out);
    } else {
        k_nms<<<BATCH, 1024, 0, stream>>>(keysA, boxes, cls, out);
    }
}